// Round 3
// baseline (1588.826 us; speedup 1.0000x reference)
//
#include <hip/hip_runtime.h>
#include <cstddef>

#define DEV static __device__ __forceinline__

constexpr int B_TOTAL = 32768;
constexpr int ROWS = 128;             // batch rows per block (2 per lane)
constexpr int NBLK = B_TOTAL / ROWS;  // 256 blocks = 1 per CU

// LDS weight layout per phase (floats), gate-interleaved columns k' = 4*unit+gate:
//   WL0 @0    : 78 rows x 100  (rows 0..49 = x(j), 50..77 = h(jh); jh 25..27 zero
//               except row 77 = BIAS STASH (multiplied by h0 pad = 0, read directly))
//   WL1 @7800 : 40 rows x 40   (rows 0..24 = h0-in, 25..27 zero, 28..37 = h1-in,
//               38 zero, row 39 = BIAS STASH)
//   WL2 @9400 : 16 rows x 16   (rows 0..9 = h1-in, 10 zero, row 11 = BIAS STASH,
//               rows 12..15 = h2 recurrent)
constexpr int WL1_OFF = 7800, WL2_OFF = 9400, W_TOTAL = 9656;
constexpr int H0_STR = 28;   // 25 units + 3 zero pad
constexpr int H1_STR = 12;   // 10 units + 2 zero pad
constexpr int HQ_OFF = 0;
constexpr int HP_OFF = B_TOTAL * 4;

DEV float fexp2(float x) { return __builtin_amdgcn_exp2f(x); }
DEV float frcp(float x) { return __builtin_amdgcn_rcpf(x); }
DEV float fsig(float x) { return frcp(1.0f + fexp2(-1.4426950408889634f * x)); }
DEV float ftanh_(float x) { return 2.0f * frcp(1.0f + fexp2(-2.8853900817779268f * x)) - 1.0f; }

DEV float elem4(const float4 v, const int jj) {
  return jj == 0 ? v.x : jj == 1 ? v.y : jj == 2 ? v.z : v.w;
}

// 2-target FMA block: NU quads x {row a, row b}.
template <int NU>
DEV void gfma1(float* __restrict__ g0, float* __restrict__ g1,
               const float4* __restrict__ w, const float va, const float vb) {
#pragma unroll
  for (int u = 0; u < NU; ++u) {
    const float4 wv = w[u];
    g0[4 * u + 0] = fmaf(wv.x, va, g0[4 * u + 0]);
    g0[4 * u + 1] = fmaf(wv.y, va, g0[4 * u + 1]);
    g0[4 * u + 2] = fmaf(wv.z, va, g0[4 * u + 2]);
    g0[4 * u + 3] = fmaf(wv.w, va, g0[4 * u + 3]);
    g1[4 * u + 0] = fmaf(wv.x, vb, g1[4 * u + 0]);
    g1[4 * u + 1] = fmaf(wv.y, vb, g1[4 * u + 1]);
    g1[4 * u + 2] = fmaf(wv.z, vb, g1[4 * u + 2]);
    g1[4 * u + 3] = fmaf(wv.w, vb, g1[4 * u + 3]);
  }
}

// 4-target FMA block: one weight read feeds steps t (a*) and t+1 (b*).
template <int NU>
DEV void gfma2(float* __restrict__ a0, float* __restrict__ a1,
               float* __restrict__ b0, float* __restrict__ b1,
               const float4* __restrict__ w,
               const float xat, const float xbt, const float xan, const float xbn) {
#pragma unroll
  for (int u = 0; u < NU; ++u) {
    const float4 wv = w[u];
    a0[4 * u + 0] = fmaf(wv.x, xat, a0[4 * u + 0]);
    a0[4 * u + 1] = fmaf(wv.y, xat, a0[4 * u + 1]);
    a0[4 * u + 2] = fmaf(wv.z, xat, a0[4 * u + 2]);
    a0[4 * u + 3] = fmaf(wv.w, xat, a0[4 * u + 3]);
    a1[4 * u + 0] = fmaf(wv.x, xbt, a1[4 * u + 0]);
    a1[4 * u + 1] = fmaf(wv.y, xbt, a1[4 * u + 1]);
    a1[4 * u + 2] = fmaf(wv.z, xbt, a1[4 * u + 2]);
    a1[4 * u + 3] = fmaf(wv.w, xbt, a1[4 * u + 3]);
    b0[4 * u + 0] = fmaf(wv.x, xan, b0[4 * u + 0]);
    b0[4 * u + 1] = fmaf(wv.y, xan, b0[4 * u + 1]);
    b0[4 * u + 2] = fmaf(wv.z, xan, b0[4 * u + 2]);
    b0[4 * u + 3] = fmaf(wv.w, xan, b0[4 * u + 3]);
    b1[4 * u + 0] = fmaf(wv.x, xbn, b1[4 * u + 0]);
    b1[4 * u + 1] = fmaf(wv.y, xbn, b1[4 * u + 1]);
    b1[4 * u + 2] = fmaf(wv.z, xbn, b1[4 * u + 2]);
    b1[4 * u + 3] = fmaf(wv.w, xbn, b1[4 * u + 3]);
  }
}

template <int NU>
DEV void activ(const float* __restrict__ g, float* __restrict__ c,
               float* __restrict__ hn) {
#pragma unroll
  for (int u = 0; u < NU; ++u) {
    const float gi_ = fsig(g[4 * u + 0]);
    const float gf  = fsig(g[4 * u + 1]);
    const float gg  = ftanh_(g[4 * u + 2]);
    const float go  = fsig(g[4 * u + 3]);
    const float cn  = fmaf(gf, c[u], gi_ * gg);
    c[u] = cn;
    hn[u] = go * ftanh_(cn);
  }
}

// Even step: x-part for steps t AND t+1 with one weight pass (gb carried),
// h-part + activation for step t. x2a/x2b point at x[row][t][0] (400 B contig).
template <int NU>
DEV void l0_even(const float* __restrict__ wl,
                 const float* __restrict__ x2a, const float* __restrict__ x2b,
                 const float* h0, const int ra, const int rb, const int u0,
                 float* __restrict__ c, float* __restrict__ hn,
                 float* __restrict__ gb0, float* __restrict__ gb1) {
  float ga0[4 * NU], ga1[4 * NU];
  {
    const float4* bq = reinterpret_cast<const float4*>(wl + 7700) + u0;  // bias row 77
#pragma unroll
    for (int u = 0; u < NU; ++u) {
      const float4 b = bq[u];
      ga0[4 * u + 0] = b.x; ga0[4 * u + 1] = b.y; ga0[4 * u + 2] = b.z; ga0[4 * u + 3] = b.w;
      ga1[4 * u + 0] = b.x; ga1[4 * u + 1] = b.y; ga1[4 * u + 2] = b.z; ga1[4 * u + 3] = b.w;
      gb0[4 * u + 0] = b.x; gb0[4 * u + 1] = b.y; gb0[4 * u + 2] = b.z; gb0[4 * u + 3] = b.w;
      gb1[4 * u + 0] = b.x; gb1[4 * u + 1] = b.y; gb1[4 * u + 2] = b.z; gb1[4 * u + 3] = b.w;
    }
  }
#pragma unroll 2
  for (int m = 0; m < 25; ++m) {
    const float2 at = *reinterpret_cast<const float2*>(x2a + 2 * m);        // x_t   row a
    const float2 an = *reinterpret_cast<const float2*>(x2a + 50 + 2 * m);   // x_t+1 row a
    const float2 bt = *reinterpret_cast<const float2*>(x2b + 2 * m);
    const float2 bn = *reinterpret_cast<const float2*>(x2b + 50 + 2 * m);
    const float4* w0 = reinterpret_cast<const float4*>(wl + (2 * m) * 100) + u0;
    const float4* w1 = reinterpret_cast<const float4*>(wl + (2 * m + 1) * 100) + u0;
    gfma2<NU>(ga0, ga1, gb0, gb1, w0, at.x, bt.x, an.x, bn.x);
    gfma2<NU>(ga0, ga1, gb0, gb1, w1, at.y, bt.y, an.y, bn.y);
  }
#pragma unroll 1
  for (int gi = 0; gi < 7; ++gi) {
    const float4 ha = *reinterpret_cast<const float4*>(h0 + ra * H0_STR + 4 * gi);
    const float4 hb = *reinterpret_cast<const float4*>(h0 + rb * H0_STR + 4 * gi);
#pragma unroll
    for (int jj = 0; jj < 4; ++jj) {
      const float4* w = reinterpret_cast<const float4*>(wl + (50 + 4 * gi + jj) * 100) + u0;
      gfma1<NU>(ga0, ga1, w, elem4(ha, jj), elem4(hb, jj));
    }
  }
  activ<NU>(ga0, c, hn);
  activ<NU>(ga1, c + 4, hn + 4);
}

// Odd step: gb already holds bias + x-part; add h-part, activate.
template <int NU>
DEV void l0_odd(const float* __restrict__ wl, const float* h0,
                const int ra, const int rb, const int u0,
                float* __restrict__ c, float* __restrict__ hn,
                float* __restrict__ g0, float* __restrict__ g1) {
#pragma unroll 1
  for (int gi = 0; gi < 7; ++gi) {
    const float4 ha = *reinterpret_cast<const float4*>(h0 + ra * H0_STR + 4 * gi);
    const float4 hb = *reinterpret_cast<const float4*>(h0 + rb * H0_STR + 4 * gi);
#pragma unroll
    for (int jj = 0; jj < 4; ++jj) {
      const float4* w = reinterpret_cast<const float4*>(wl + (50 + 4 * gi + jj) * 100) + u0;
      gfma1<NU>(g0, g1, w, elem4(ha, jj), elem4(hb, jj));
    }
  }
  activ<NU>(g0, c, hn);
  activ<NU>(g1, c + 4, hn + 4);
}

template <int NU>
DEV void l1_fw(const float* __restrict__ wl, const float* h0, const float* h1,
               const int ra, const int rb, const int u0,
               float* __restrict__ c, float* __restrict__ hn) {
  float g0[4 * NU], g1[4 * NU];
  {
    const float4* bq = reinterpret_cast<const float4*>(wl + 1560) + u0;  // bias row 39
#pragma unroll
    for (int u = 0; u < NU; ++u) {
      const float4 b = bq[u];
      g0[4 * u + 0] = b.x; g0[4 * u + 1] = b.y; g0[4 * u + 2] = b.z; g0[4 * u + 3] = b.w;
      g1[4 * u + 0] = b.x; g1[4 * u + 1] = b.y; g1[4 * u + 2] = b.z; g1[4 * u + 3] = b.w;
    }
  }
#pragma unroll 1
  for (int gi = 0; gi < 7; ++gi) {
    const float4 ha = *reinterpret_cast<const float4*>(h0 + ra * H0_STR + 4 * gi);
    const float4 hb = *reinterpret_cast<const float4*>(h0 + rb * H0_STR + 4 * gi);
#pragma unroll
    for (int jj = 0; jj < 4; ++jj) {
      const float4* w = reinterpret_cast<const float4*>(wl + (4 * gi + jj) * 40) + u0;
      gfma1<NU>(g0, g1, w, elem4(ha, jj), elem4(hb, jj));
    }
  }
#pragma unroll 1
  for (int gi = 0; gi < 3; ++gi) {
    const float4 ha = *reinterpret_cast<const float4*>(h1 + ra * H1_STR + 4 * gi);
    const float4 hb = *reinterpret_cast<const float4*>(h1 + rb * H1_STR + 4 * gi);
#pragma unroll
    for (int jj = 0; jj < 4; ++jj) {
      const float4* w = reinterpret_cast<const float4*>(wl + (28 + 4 * gi + jj) * 40) + u0;
      gfma1<NU>(g0, g1, w, elem4(ha, jj), elem4(hb, jj));
    }
  }
  activ<NU>(g0, c, hn);
  activ<NU>(g1, c + 2, hn + 2);
}

// Layer 2 (wave 7 only): all 4 units, recurrent h in registers.
DEV void l2_fw(const float* __restrict__ wl, const float* h1,
               const int ra, const int rb, float* __restrict__ c,
               float* __restrict__ h2) {
  float g0[16], g1[16];
  {
    const float4* bq = reinterpret_cast<const float4*>(wl + 176);  // bias row 11
#pragma unroll
    for (int u = 0; u < 4; ++u) {
      const float4 b = bq[u];
      g0[4 * u + 0] = b.x; g0[4 * u + 1] = b.y; g0[4 * u + 2] = b.z; g0[4 * u + 3] = b.w;
      g1[4 * u + 0] = b.x; g1[4 * u + 1] = b.y; g1[4 * u + 2] = b.z; g1[4 * u + 3] = b.w;
    }
  }
#pragma unroll 1
  for (int gi = 0; gi < 3; ++gi) {
    const float4 ha = *reinterpret_cast<const float4*>(h1 + ra * H1_STR + 4 * gi);
    const float4 hb = *reinterpret_cast<const float4*>(h1 + rb * H1_STR + 4 * gi);
#pragma unroll
    for (int jj = 0; jj < 4; ++jj) {
      const float4* w = reinterpret_cast<const float4*>(wl + (4 * gi + jj) * 16);
      gfma1<4>(g0, g1, w, elem4(ha, jj), elem4(hb, jj));
    }
  }
#pragma unroll
  for (int jj = 0; jj < 4; ++jj) {  // recurrent: reads all h2 before activ writes
    const float4* w = reinterpret_cast<const float4*>(wl + (12 + jj) * 16);
    gfma1<4>(g0, g1, w, h2[jj], h2[4 + jj]);
  }
  activ<4>(g0, c, h2);
  activ<4>(g1, c + 4, h2 + 4);
}

// 256 blocks x 512 threads (8 waves, 2/SIMD, 1 block/CU). Lane r owns rows r,
// r+64. Unit split: L0 {4,4,3,3,3,3,3,2}, L1 {0,0,2,2,2,2,1,1}, L2 on wave 7.
// Steps processed in pairs: even step does the x-projection for BOTH steps.
__global__ __launch_bounds__(512, 2) void lstm_towers(
    const float* __restrict__ q, const float* __restrict__ p,
    const float* __restrict__ qWih0, const float* __restrict__ qWhh0, const float* __restrict__ qb0,
    const float* __restrict__ qWih1, const float* __restrict__ qWhh1, const float* __restrict__ qb1,
    const float* __restrict__ qWih2, const float* __restrict__ qWhh2, const float* __restrict__ qb2,
    const float* __restrict__ pWih0, const float* __restrict__ pWhh0, const float* __restrict__ pb0,
    const float* __restrict__ pWih1, const float* __restrict__ pWhh1, const float* __restrict__ pb1,
    const float* __restrict__ pWih2, const float* __restrict__ pWhh2, const float* __restrict__ pb2,
    float* __restrict__ hq_out, float* __restrict__ hp_out) {
  __shared__ float wlds[W_TOTAL];          // 38624 B
  __shared__ float h0s[ROWS * H0_STR];     // 14336 B (single buffer)
  __shared__ float h1s[2 * ROWS * H1_STR]; // 12288 B (double buffer)

  const int tid = threadIdx.x;
  const int r = tid & 63;
  const int wid = tid >> 6;  // 0..7
  const int row0 = blockIdx.x * ROWS;
  const int ra = r, rb = r + 64;

  const int u00 = __builtin_amdgcn_readfirstlane(
      wid < 2 ? 4 * wid : (wid < 7 ? 8 + 3 * (wid - 2) : 23));
  const int u01 = __builtin_amdgcn_readfirstlane(
      wid < 6 ? 2 * (wid - 2) : 8 + (wid - 6));  // valid for wid>=2

  const float* wl0 = wlds;
  const float* wl1 = wlds + WL1_OFF;
  const float* wl2 = wlds + WL2_OFF;

#pragma unroll 1
  for (int phase = 0; phase < 2; ++phase) {
    const bool isp = (phase == 1);
    const float* __restrict__ x = isp ? p : q;
    const int T = isp ? 50 : 12;
    const float* Wih0 = isp ? pWih0 : qWih0; const float* Whh0 = isp ? pWhh0 : qWhh0;
    const float* b0g  = isp ? pb0   : qb0;
    const float* Wih1 = isp ? pWih1 : qWih1; const float* Whh1 = isp ? pWhh1 : qWhh1;
    const float* b1g  = isp ? pb1   : qb1;
    const float* Wih2 = isp ? pWih2 : qWih2; const float* Whh2 = isp ? pWhh2 : qWhh2;
    const float* b2g  = isp ? pb2   : qb2;
    float* __restrict__ hout_g = isp ? hp_out : hq_out;

    __syncthreads();  // prior phase fully done with LDS before rewrite

    // ---- transpose + gate-interleave weights into LDS (+ bias stash rows) ----
    for (int e = tid; e < W_TOTAL; e += 512) {
      float v = 0.0f;
      if (e < WL1_OFF) {
        const int j = e / 100, k = e % 100, u = k >> 2, gt = k & 3, rr = gt * 25 + u;
        if (j < 50) v = Wih0[rr * 50 + j];
        else if (j < 75) v = Whh0[rr * 25 + (j - 50)];
        else if (j == 77) v = b0g[gt * 25 + u];          // bias stash
      } else if (e < WL2_OFF) {
        const int i = e - WL1_OFF, j = i / 40, k = i % 40, u = k >> 2, gt = k & 3;
        const int rr = gt * 10 + u;
        if (j < 25) v = Wih1[rr * 25 + j];
        else if (j >= 28 && j < 38) v = Whh1[rr * 10 + (j - 28)];
        else if (j == 39) v = b1g[gt * 10 + u];          // bias stash
      } else {
        const int i = e - WL2_OFF, j = i / 16, k = i % 16, u = k >> 2, gt = k & 3;
        const int rr = gt * 4 + u;
        if (j < 10) v = Wih2[rr * 10 + j];
        else if (j == 11) v = b2g[gt * 4 + u];           // bias stash
        else if (j >= 12) v = Whh2[rr * 4 + (j - 12)];
      }
      wlds[e] = v;
    }
    for (int i = tid; i < ROWS * H0_STR; i += 512) h0s[i] = 0.0f;
    for (int i = tid; i < 2 * ROWS * H1_STR; i += 512) h1s[i] = 0.0f;

    float c0[8] = {}, hn0[8];
    float c1[4] = {}, hn1[4];
    float c2[8] = {}, h2r[8] = {};
    float gb0[16], gb1[16];

    const float* x2a = x + (size_t)(row0 + ra) * T * 50;
    const float* x2b = x + (size_t)(row0 + rb) * T * 50;

    __syncthreads();  // weights + zeroed state visible

    int s = 0;
#pragma unroll 1
    for (int tp = 0; tp < T; tp += 2) {
      // ================= even step t = tp =================
      if (wid < 2)      l0_even<4>(wl0, x2a, x2b, h0s, ra, rb, u00, c0, hn0, gb0, gb1);
      else if (wid < 7) l0_even<3>(wl0, x2a, x2b, h0s, ra, rb, u00, c0, hn0, gb0, gb1);
      else              l0_even<2>(wl0, x2a, x2b, h0s, ra, rb, u00, c0, hn0, gb0, gb1);
      __syncthreads();  // bar1: all h0_{t-1} reads done
      {
        float* da = &h0s[ra * H0_STR + u00];
        float* db = &h0s[rb * H0_STR + u00];
        if (wid < 2) {
          da[0] = hn0[0]; da[1] = hn0[1]; da[2] = hn0[2]; da[3] = hn0[3];
          db[0] = hn0[4]; db[1] = hn0[5]; db[2] = hn0[6]; db[3] = hn0[7];
        } else if (wid < 7) {
          da[0] = hn0[0]; da[1] = hn0[1]; da[2] = hn0[2];
          db[0] = hn0[4]; db[1] = hn0[5]; db[2] = hn0[6];
        } else {
          da[0] = hn0[0]; da[1] = hn0[1];
          db[0] = hn0[4]; db[1] = hn0[5];
        }
      }
      __syncthreads();  // bar2: h0_t visible
      {
        const float* h1rd = h1s + s * (ROWS * H1_STR);
        float* h1wr = h1s + (s ^ 1) * (ROWS * H1_STR);
        if (wid >= 2 && wid < 6) l1_fw<2>(wl1, h0s, h1rd, ra, rb, u01, c1, hn1);
        else if (wid >= 6)       l1_fw<1>(wl1, h0s, h1rd, ra, rb, u01, c1, hn1);
        if (wid >= 2) {
          float* ea = &h1wr[ra * H1_STR + u01];
          float* eb = &h1wr[rb * H1_STR + u01];
          if (wid < 6) { ea[0] = hn1[0]; ea[1] = hn1[1]; eb[0] = hn1[2]; eb[1] = hn1[3]; }
          else         { ea[0] = hn1[0]; eb[0] = hn1[2]; }
        }
        __syncthreads();  // bar3: h1_t visible
        if (wid == 7) l2_fw(wl2, h1wr, ra, rb, c2, h2r);
      }
      s ^= 1;
      // ================= odd step t = tp+1 =================
      if (wid < 2)      l0_odd<4>(wl0, h0s, ra, rb, u00, c0, hn0, gb0, gb1);
      else if (wid < 7) l0_odd<3>(wl0, h0s, ra, rb, u00, c0, hn0, gb0, gb1);
      else              l0_odd<2>(wl0, h0s, ra, rb, u00, c0, hn0, gb0, gb1);
      __syncthreads();  // bar1
      {
        float* da = &h0s[ra * H0_STR + u00];
        float* db = &h0s[rb * H0_STR + u00];
        if (wid < 2) {
          da[0] = hn0[0]; da[1] = hn0[1]; da[2] = hn0[2]; da[3] = hn0[3];
          db[0] = hn0[4]; db[1] = hn0[5]; db[2] = hn0[6]; db[3] = hn0[7];
        } else if (wid < 7) {
          da[0] = hn0[0]; da[1] = hn0[1]; da[2] = hn0[2];
          db[0] = hn0[4]; db[1] = hn0[5]; db[2] = hn0[6];
        } else {
          da[0] = hn0[0]; da[1] = hn0[1];
          db[0] = hn0[4]; db[1] = hn0[5];
        }
      }
      __syncthreads();  // bar2
      {
        const float* h1rd = h1s + s * (ROWS * H1_STR);
        float* h1wr = h1s + (s ^ 1) * (ROWS * H1_STR);
        if (wid >= 2 && wid < 6) l1_fw<2>(wl1, h0s, h1rd, ra, rb, u01, c1, hn1);
        else if (wid >= 6)       l1_fw<1>(wl1, h0s, h1rd, ra, rb, u01, c1, hn1);
        if (wid >= 2) {
          float* ea = &h1wr[ra * H1_STR + u01];
          float* eb = &h1wr[rb * H1_STR + u01];
          if (wid < 6) { ea[0] = hn1[0]; ea[1] = hn1[1]; eb[0] = hn1[2]; eb[1] = hn1[3]; }
          else         { ea[0] = hn1[0]; eb[0] = hn1[2]; }
        }
        __syncthreads();  // bar3
        if (wid == 7) l2_fw(wl2, h1wr, ra, rb, c2, h2r);
      }
      s ^= 1;
      x2a += 100; x2b += 100;
    }
    if (wid == 7) {
      reinterpret_cast<float4*>(hout_g)[row0 + ra] =
          make_float4(h2r[0], h2r[1], h2r[2], h2r[3]);
      reinterpret_cast<float4*>(hout_g)[row0 + rb] =
          make_float4(h2r[4], h2r[5], h2r[6], h2r[7]);
    }
  }
}

// ---------------- head: softmax((hq*hp) @ fW^T + fb) -------------------------
__global__ __launch_bounds__(256) void combine_head(
    const float* __restrict__ hq, const float* __restrict__ hp,
    const float* __restrict__ fW, const float* __restrict__ fb,
    float* __restrict__ out) {
  const int b = blockIdx.x * blockDim.x + (int)threadIdx.x;
  if (b >= B_TOTAL) return;
  const float4 vq = reinterpret_cast<const float4*>(hq)[b];
  const float4 vp = reinterpret_cast<const float4*>(hp)[b];
  const float s0 = vq.x * vp.x, s1 = vq.y * vp.y, s2 = vq.z * vp.z, s3 = vq.w * vp.w;
  float l0 = fb[0], l1 = fb[1];
  l0 = fmaf(s0, fW[0], l0); l0 = fmaf(s1, fW[1], l0); l0 = fmaf(s2, fW[2], l0); l0 = fmaf(s3, fW[3], l0);
  l1 = fmaf(s0, fW[4], l1); l1 = fmaf(s1, fW[5], l1); l1 = fmaf(s2, fW[6], l1); l1 = fmaf(s3, fW[7], l1);
  const float m = fmaxf(l0, l1);
  const float e0 = fexp2(1.4426950408889634f * (l0 - m));
  const float e1 = fexp2(1.4426950408889634f * (l1 - m));
  const float inv = frcp(e0 + e1);
  reinterpret_cast<float2*>(out)[b] = make_float2(e0 * inv, e1 * inv);
}

extern "C" void kernel_launch(void* const* d_in, const int* in_sizes, int n_in,
                              void* d_out, int out_size, void* d_ws, size_t ws_size,
                              hipStream_t stream) {
  (void)in_sizes; (void)n_in; (void)out_size; (void)ws_size;
  const float* q = (const float*)d_in[0];
  const float* p = (const float*)d_in[1];
  float* ws = (float*)d_ws;

  lstm_towers<<<NBLK, 512, 0, stream>>>(
      q, p,
      (const float*)d_in[2], (const float*)d_in[3], (const float*)d_in[4],
      (const float*)d_in[5], (const float*)d_in[6], (const float*)d_in[7],
      (const float*)d_in[8], (const float*)d_in[9], (const float*)d_in[10],
      (const float*)d_in[11], (const float*)d_in[12], (const float*)d_in[13],
      (const float*)d_in[14], (const float*)d_in[15], (const float*)d_in[16],
      (const float*)d_in[17], (const float*)d_in[18], (const float*)d_in[19],
      ws + HQ_OFF, ws + HP_OFF);

  combine_head<<<B_TOTAL / 256, 256, 0, stream>>>(
      ws + HQ_OFF, ws + HP_OFF,
      (const float*)d_in[20], (const float*)d_in[21], (float*)d_out);
}